// Round 13
// baseline (485.114 us; speedup 1.0000x reference)
//
#include <hip/hip_runtime.h>

// 2-layer LSTM (B=4096, T=512, H=50) + FC head.
// R13 vs R12 (537 us steady; trans-issue ~640 cyc/wave/step dominant,
// 2 waves/SIMD fixed by AGPR-resident weights):
//  (1) FIN with COMMON-DENOMINATOR gates: 5 exp2 + 2 rcp per cell (was 10
//      trans). Unlike R11's paired-rcp (serial, regressed), the 4 cells
//      stay independent; merging is within-cell only. Clamps required
//      (preacts >= -20, tanh-in >= -10) else inf-inf = NaN.
//  (2) h-plane order [kt][s][b][hh][e]: A-frag = ONE ds_read_b128 at
//      16B*lane (dense, conflict-free; elem order hh*4+e == MFMA k-map).
//      L1 8->4 ds ops, L0 4->2.
//  (3) skeleton / barriers / parities / STAGE verbatim from R12.

typedef __attribute__((ext_vector_type(8))) _Float16 half8;
typedef __attribute__((ext_vector_type(4))) float f32x4;

#define LOG2E 1.44269504088896340736f

__device__ __forceinline__ float rcp_(float x) { return __builtin_amdgcn_rcpf(x); }
__device__ __forceinline__ float exp2_(float x) { return __builtin_amdgcn_exp2f(x); }
__device__ __forceinline__ f32x4 mfma16(half8 a, half8 b, f32x4 c) {
  return __builtin_amdgcn_mfma_f32_16x16x32_f16(a, b, c, 0, 0, 0);
}

union ABu16 { uint4 u; half8 v; };
__device__ __forceinline__ half8 rdfrag(const _Float16* p) {
  ABu16 t;
  t.u = *(const uint4*)p;
  return t.v;
}

// B-fragment (f16 hi + lo) of W (50x50 logical) for output column (n,gate);
// k = kbase + 16*(e>>2) + 4*lg + (e&3).
__device__ __forceinline__ void loadW(const float* __restrict__ W, int n,
                                      int gate, int kbase, int lg,
                                      half8& h8, half8& l8) {
#pragma unroll
  for (int e = 0; e < 8; ++e) {
    const int k = kbase + 16 * (e >> 2) + 4 * lg + (e & 3);
    const bool v = (n < 50) && (k < 50);
    const float w = v ? W[(gate * 50 + n) * 50 + k] : 0.f;
    const _Float16 hi = (_Float16)w;
    h8[e] = hi;
    l8[e] = (_Float16)(w - (float)hi);
  }
}

#define GATES(X) X(0) X(1) X(2) X(3)

// Gate finish for batch row r: 5 exp2 + 2 rcp.
//   c' = (c*P + (1-u)*pf) / (P*pf),  P = (1+e_i)(1+u)
//   h  = (1-v) / (po*(1+v)),         v = e^{-2*clamp(c')}
#define FINX(r, PH, WPc)                                                 \
  {                                                                      \
    const float xi = fmaxf(ai[r], -20.f), xf = fmaxf(af[r], -20.f);      \
    const float xg = fmaxf(ag[r], -20.f), xo = fmaxf(ao[r], -20.f);      \
    const float ei = exp2_(-LOG2E * xi), ef = exp2_(-LOG2E * xf);        \
    const float uu = exp2_(-2.f * LOG2E * xg), eo = exp2_(-LOG2E * xo);  \
    const float pi = 1.f + ei, pf = 1.f + ef;                            \
    const float pu = 1.f + uu, po = 1.f + eo;                            \
    const float P = pi * pu;                                             \
    const float R = rcp_(P * pf);                                        \
    const float num = cc##r * P + (1.f - uu) * pf;                       \
    cc##r = num * R;                                                     \
    const float ct = fmaxf(cc##r, -10.f);                                \
    const float v = exp2_(-2.f * LOG2E * ct);                            \
    const float R2 = rcp_(po * (1.f + v));                               \
    PH[WPc][woff + 8 * (r)] = (_Float16)((1.f - v) * R2);                \
  }

__global__ __launch_bounds__(512) void lstm2_kernel(
    const float* __restrict__ x,
    const float* __restrict__ Wih0, const float* __restrict__ Whh0,
    const float* __restrict__ bih0, const float* __restrict__ bhh0,
    const float* __restrict__ Wih1, const float* __restrict__ Whh1,
    const float* __restrict__ bih1, const float* __restrict__ bhh1,
    const float* __restrict__ fcW, const float* __restrict__ fcb,
    float* __restrict__ out) {
  const int tid = threadIdx.x;
  const int lane = tid & 63;
  const int wv = tid >> 6;      // wave 0..7
  const int wg = wv & 3;        // unit-group within layer role
  const bool isL1 = wv >= 4;    // waves 4-7: layer 1 (lagged one step)
  const int lg = lane >> 4;     // 0..3 (k-slice / batch-group)
  const int l15 = lane & 15;
  const int bbase = blockIdx.x * 16;

  // h planes (f16): idx(u,b) = (u>>5)*512 + ((u>>2)&3)*128 + b*8 +
  // ((u>>4)&1)*4 + (u&3). A-frag for k-tile kt = b128 at [kt*512 + 8*lane].
  __shared__ __align__(16) _Float16 H0[2][1024], H1[2][1024];
  __shared__ float xs2[64][16];    // x chunk: [t within chunk][batch]
  __shared__ float ldspad[18688];  // 74.75 KB pin -> ~87 KB total, 1 blk/CU

  ((volatile float*)ldspad)[tid] = 0.f;

  for (int i = tid; i < 1024; i += 512) {  // zero both parities of both planes
    ((unsigned int*)H0)[i] = 0u;
    ((unsigned int*)H1)[i] = 0u;
  }

  const int lane8 = lane * 8;   // f16 index of this lane's b128 A-frag slot
  const int u = 16 * wg + l15;  // this lane's output unit
  const bool uv = (u < 50);
  // write base for (u, batches 4lg..4lg+3): +8 per batch row
  const int woff = ((u >> 5) << 9) + (((u >> 2) & 3) << 7) + ((4 * lg) << 3) +
                   (((u >> 4) & 1) << 2) + (u & 3);

#define STAGE(c)                                                        \
  {                                                                     \
    const int b_ = tid >> 4, fg_ = tid & 15;                            \
    const float4 v_ = *(const float4*)&x[(size_t)(bbase + b_) * 512 +   \
                                         (c) * 64 + 4 * fg_];           \
    xs2[4 * fg_ + 0][b_] = v_.x; xs2[4 * fg_ + 1][b_] = v_.y;           \
    xs2[4 * fg_ + 2][b_] = v_.z; xs2[4 * fg_ + 3][b_] = v_.w;           \
  }

  if (!isL1) {
    // ================= LAYER-0 WAVES (tid < 256) =================
#define DECL0(G) half8 W0h_##G, W0l_##G, W1h_##G, W1l_##G;  \
    float bi_##G = 0.f, wx_##G = 0.f;
    GATES(DECL0)
#define LOAD0(G)                                              \
    { loadW(Whh0, u, G, 0, lg, W0h_##G, W0l_##G);             \
      loadW(Whh0, u, G, 32, lg, W1h_##G, W1l_##G);            \
      if (uv) {                                               \
        bi_##G = bih0[G * 50 + u] + bhh0[G * 50 + u];         \
        wx_##G = Wih0[G * 50 + u];                            \
      } }
    GATES(LOAD0)
    float cc0 = 0.f, cc1 = 0.f, cc2 = 0.f, cc3 = 0.f;

#define MM0(G, ACC)                                           \
    ACC = mfma16(f0, W0h_##G, ACC);                           \
    ACC = mfma16(f0, W0l_##G, ACC);                           \
    ACC = mfma16(f1, W1h_##G, ACC);                           \
    ACC = mfma16(f1, W1l_##G, ACC);

#define L0STEP(RP, WP, tm)                                                  \
    { const half8 f0 = rdfrag(&H0[RP][lane8]);                              \
      const half8 f1 = rdfrag(&H0[RP][512 + lane8]);                        \
      const float4 xv = *(const float4*)&xs2[tm][4 * lg];                   \
      f32x4 ai = {fmaf(xv.x, wx_0, bi_0), fmaf(xv.y, wx_0, bi_0),           \
                  fmaf(xv.z, wx_0, bi_0), fmaf(xv.w, wx_0, bi_0)};          \
      f32x4 af = {fmaf(xv.x, wx_1, bi_1), fmaf(xv.y, wx_1, bi_1),           \
                  fmaf(xv.z, wx_1, bi_1), fmaf(xv.w, wx_1, bi_1)};          \
      f32x4 ag = {fmaf(xv.x, wx_2, bi_2), fmaf(xv.y, wx_2, bi_2),           \
                  fmaf(xv.z, wx_2, bi_2), fmaf(xv.w, wx_2, bi_2)};          \
      f32x4 ao = {fmaf(xv.x, wx_3, bi_3), fmaf(xv.y, wx_3, bi_3),           \
                  fmaf(xv.z, wx_3, bi_3), fmaf(xv.w, wx_3, bi_3)};          \
      MM0(0, ai) MM0(1, af) MM0(2, ag) MM0(3, ao)                           \
      FINX(0, H0, WP) FINX(1, H0, WP) FINX(2, H0, WP) FINX(3, H0, WP) }

    STAGE(0) __syncthreads();
    L0STEP(1, 0, 0) __syncthreads();  // tt=0: read zeros(parity1), write p0
    for (int it = 0; it < 255; ++it) {
      const int todd = 2 * it + 1;
      L0STEP(0, 1, (todd & 63)) __syncthreads();
      const int tev = todd + 1;
      if ((tev & 63) == 0) { STAGE(tev >> 6) __syncthreads(); }
      L0STEP(1, 0, (tev & 63)) __syncthreads();
    }
    L0STEP(0, 1, 63) __syncthreads();  // tt=511
    __syncthreads();                   // matches L1 epilogue barrier
  } else {
    // ================= LAYER-1 WAVES =================
#define DECL1(G) half8 I0h_##G, I0l_##G, I1h_##G, I1l_##G,    \
        R0h_##G, R0l_##G, R1h_##G, R1l_##G;                   \
    float bi_##G = 0.f;
    GATES(DECL1)
#define LOAD1(G)                                              \
    { loadW(Wih1, u, G, 0, lg, I0h_##G, I0l_##G);             \
      loadW(Wih1, u, G, 32, lg, I1h_##G, I1l_##G);            \
      loadW(Whh1, u, G, 0, lg, R0h_##G, R0l_##G);             \
      loadW(Whh1, u, G, 32, lg, R1h_##G, R1l_##G);            \
      if (uv) bi_##G = bih1[G * 50 + u] + bhh1[G * 50 + u]; }
    GATES(LOAD1)
    float cc0 = 0.f, cc1 = 0.f, cc2 = 0.f, cc3 = 0.f;

#define MM1(G, ACC)                                           \
    ACC = mfma16(f0, I0h_##G, ACC);                           \
    ACC = mfma16(f0, I0l_##G, ACC);                           \
    ACC = mfma16(f1, I1h_##G, ACC);                           \
    ACC = mfma16(f1, I1l_##G, ACC);                           \
    ACC = mfma16(g0, R0h_##G, ACC);                           \
    ACC = mfma16(g0, R0l_##G, ACC);                           \
    ACC = mfma16(g1, R1h_##G, ACC);                           \
    ACC = mfma16(g1, R1l_##G, ACC);

#define L1STEP(P0, R1, W1)                                                  \
    { const half8 f0 = rdfrag(&H0[P0][lane8]);                              \
      const half8 f1 = rdfrag(&H0[P0][512 + lane8]);                        \
      const half8 g0 = rdfrag(&H1[R1][lane8]);                              \
      const half8 g1 = rdfrag(&H1[R1][512 + lane8]);                        \
      f32x4 ai = {bi_0, bi_0, bi_0, bi_0};                                  \
      f32x4 af = {bi_1, bi_1, bi_1, bi_1};                                  \
      f32x4 ag = {bi_2, bi_2, bi_2, bi_2};                                  \
      f32x4 ao = {bi_3, bi_3, bi_3, bi_3};                                  \
      MM1(0, ai) MM1(1, af) MM1(2, ag) MM1(3, ao)                           \
      FINX(0, H1, W1) FINX(1, H1, W1) FINX(2, H1, W1) FINX(3, H1, W1) }

    __syncthreads(); __syncthreads();  // mirror peel barriers (tt=0 skip)
    for (int it = 0; it < 255; ++it) {
      // tt odd: h0[tt-1]=p0, h1[tt-2]=p1, write h1[tt-1]=p0
      L1STEP(0, 1, 0) __syncthreads();
      if (((2 * it + 2) & 63) == 0) __syncthreads();  // mirror stage barrier
      // tt even: h0[tt-1]=p1, h1[tt-2]=p0, write h1[tt-1]=p1
      L1STEP(1, 0, 1) __syncthreads();
    }
    L1STEP(0, 1, 0) __syncthreads();  // tt=511 -> h1[510]
    L1STEP(1, 0, 1) __syncthreads();  // epilogue -> h1[511] (parity 1)
  }

  // ---- FC head: out[b] = fc_b + sum_j fcW[j] * h1[511][b][j] ----
  if (tid < 16) {
    float s = fcb[0];
    for (int j = 0; j < 50; ++j) {
      const int idx = ((j >> 5) << 9) + (((j >> 2) & 3) << 7) + (tid << 3) +
                      (((j >> 4) & 1) << 2) + (j & 3);
      s += fcW[j] * (float)H1[1][idx];
    }
    out[bbase + tid] = s;
  }
}

extern "C" void kernel_launch(void* const* d_in, const int* in_sizes, int n_in,
                              void* d_out, int out_size, void* d_ws, size_t ws_size,
                              hipStream_t stream) {
  const float* x    = (const float*)d_in[0];
  const float* Wih0 = (const float*)d_in[1];
  const float* Whh0 = (const float*)d_in[2];
  const float* bih0 = (const float*)d_in[3];
  const float* bhh0 = (const float*)d_in[4];
  const float* Wih1 = (const float*)d_in[5];
  const float* Whh1 = (const float*)d_in[6];
  const float* bih1 = (const float*)d_in[7];
  const float* bhh1 = (const float*)d_in[8];
  const float* fcW  = (const float*)d_in[9];
  const float* fcb  = (const float*)d_in[10];
  float* out = (float*)d_out;

  const int B = out_size;          // 4096
  const int blocks = B / 16;       // 256
  lstm2_kernel<<<dim3(blocks), dim3(512), 0, stream>>>(
      x, Wih0, Whh0, bih0, bhh0, Wih1, Whh1, bih1, bhh1, fcW, fcb, out);
}

// Round 14
// 477.220 us; speedup vs baseline: 1.0165x; 1.0165x over previous
//
#include <hip/hip_runtime.h>

// 2-layer LSTM (B=4096, T=512, H=50) + FC head.
// R14 = controlled isolation: R13's b128 A-frag layout + R12's FIN math.
//  - R12 {old layout, FIN-simple} = 537 us steady
//  - R13 {b128 layout, FIN-commondenom} = 548 us steady (FINX regressed:
//    more VALU ops + deeper serial chain; trans count was NOT the limiter
//    -- second confirmation after R11's paired-rcp)
//  - R14 {b128 layout, FIN-simple}: isolates both effects.
// FIN: 4 independent sigm + 2 tanh (10 trans), no clamps (saturation via
// inf*rcp is well-defined), shallow c-chain (one fma). Everything else
// byte-identical to R13.

typedef __attribute__((ext_vector_type(8))) _Float16 half8;
typedef __attribute__((ext_vector_type(4))) float f32x4;

#define LOG2E 1.44269504088896340736f

__device__ __forceinline__ float rcp_(float x) { return __builtin_amdgcn_rcpf(x); }
__device__ __forceinline__ float exp2_(float x) { return __builtin_amdgcn_exp2f(x); }
__device__ __forceinline__ float sigm(float x) {
  return rcp_(1.f + exp2_(-LOG2E * x));
}
__device__ __forceinline__ float tanh_(float x) {
  return 1.f - 2.f * rcp_(1.f + exp2_(2.f * LOG2E * x));
}
__device__ __forceinline__ f32x4 mfma16(half8 a, half8 b, f32x4 c) {
  return __builtin_amdgcn_mfma_f32_16x16x32_f16(a, b, c, 0, 0, 0);
}

union ABu16 { uint4 u; half8 v; };
__device__ __forceinline__ half8 rdfrag(const _Float16* p) {
  ABu16 t;
  t.u = *(const uint4*)p;
  return t.v;
}

// B-fragment (f16 hi + lo) of W (50x50 logical) for output column (n,gate);
// k = kbase + 16*(e>>2) + 4*lg + (e&3).
__device__ __forceinline__ void loadW(const float* __restrict__ W, int n,
                                      int gate, int kbase, int lg,
                                      half8& h8, half8& l8) {
#pragma unroll
  for (int e = 0; e < 8; ++e) {
    const int k = kbase + 16 * (e >> 2) + 4 * lg + (e & 3);
    const bool v = (n < 50) && (k < 50);
    const float w = v ? W[(gate * 50 + n) * 50 + k] : 0.f;
    const _Float16 hi = (_Float16)w;
    h8[e] = hi;
    l8[e] = (_Float16)(w - (float)hi);
  }
}

#define GATES(X) X(0) X(1) X(2) X(3)

// Gate finish (R12 form): 4 indep sigm + 2 tanh, shallow c-chain.
#define FINR(r, PH, WPc)                                      \
  {                                                           \
    const float i_ = sigm(ai[r]), ff = sigm(af[r]);           \
    const float g_ = tanh_(ag[r]), o_ = sigm(ao[r]);          \
    cc##r = ff * cc##r + i_ * g_;                             \
    PH[WPc][woff + 8 * (r)] = (_Float16)(o_ * tanh_(cc##r));  \
  }

__global__ __launch_bounds__(512) void lstm2_kernel(
    const float* __restrict__ x,
    const float* __restrict__ Wih0, const float* __restrict__ Whh0,
    const float* __restrict__ bih0, const float* __restrict__ bhh0,
    const float* __restrict__ Wih1, const float* __restrict__ Whh1,
    const float* __restrict__ bih1, const float* __restrict__ bhh1,
    const float* __restrict__ fcW, const float* __restrict__ fcb,
    float* __restrict__ out) {
  const int tid = threadIdx.x;
  const int lane = tid & 63;
  const int wv = tid >> 6;      // wave 0..7
  const int wg = wv & 3;        // unit-group within layer role
  const bool isL1 = wv >= 4;    // waves 4-7: layer 1 (lagged one step)
  const int lg = lane >> 4;     // 0..3 (k-slice / batch-group)
  const int l15 = lane & 15;
  const int bbase = blockIdx.x * 16;

  // h planes (f16): idx(u,b) = (u>>5)*512 + ((u>>2)&3)*128 + b*8 +
  // ((u>>4)&1)*4 + (u&3). A-frag for k-tile kt = b128 at [kt*512 + 8*lane].
  __shared__ __align__(16) _Float16 H0[2][1024], H1[2][1024];
  __shared__ float xs2[64][16];    // x chunk: [t within chunk][batch]
  __shared__ float ldspad[18688];  // 74.75 KB pin -> ~87 KB total, 1 blk/CU

  ((volatile float*)ldspad)[tid] = 0.f;

  for (int i = tid; i < 1024; i += 512) {  // zero both parities of both planes
    ((unsigned int*)H0)[i] = 0u;
    ((unsigned int*)H1)[i] = 0u;
  }

  const int lane8 = lane * 8;   // f16 index of this lane's b128 A-frag slot
  const int u = 16 * wg + l15;  // this lane's output unit
  const bool uv = (u < 50);
  // write base for (u, batches 4lg..4lg+3): +8 per batch row
  const int woff = ((u >> 5) << 9) + (((u >> 2) & 3) << 7) + ((4 * lg) << 3) +
                   (((u >> 4) & 1) << 2) + (u & 3);

#define STAGE(c)                                                        \
  {                                                                     \
    const int b_ = tid >> 4, fg_ = tid & 15;                            \
    const float4 v_ = *(const float4*)&x[(size_t)(bbase + b_) * 512 +   \
                                         (c) * 64 + 4 * fg_];           \
    xs2[4 * fg_ + 0][b_] = v_.x; xs2[4 * fg_ + 1][b_] = v_.y;           \
    xs2[4 * fg_ + 2][b_] = v_.z; xs2[4 * fg_ + 3][b_] = v_.w;           \
  }

  if (!isL1) {
    // ================= LAYER-0 WAVES (tid < 256) =================
#define DECL0(G) half8 W0h_##G, W0l_##G, W1h_##G, W1l_##G;  \
    float bi_##G = 0.f, wx_##G = 0.f;
    GATES(DECL0)
#define LOAD0(G)                                              \
    { loadW(Whh0, u, G, 0, lg, W0h_##G, W0l_##G);             \
      loadW(Whh0, u, G, 32, lg, W1h_##G, W1l_##G);            \
      if (uv) {                                               \
        bi_##G = bih0[G * 50 + u] + bhh0[G * 50 + u];         \
        wx_##G = Wih0[G * 50 + u];                            \
      } }
    GATES(LOAD0)
    float cc0 = 0.f, cc1 = 0.f, cc2 = 0.f, cc3 = 0.f;

#define MM0(G, ACC)                                           \
    ACC = mfma16(f0, W0h_##G, ACC);                           \
    ACC = mfma16(f0, W0l_##G, ACC);                           \
    ACC = mfma16(f1, W1h_##G, ACC);                           \
    ACC = mfma16(f1, W1l_##G, ACC);

#define L0STEP(RP, WP, tm)                                                  \
    { const half8 f0 = rdfrag(&H0[RP][lane8]);                              \
      const half8 f1 = rdfrag(&H0[RP][512 + lane8]);                        \
      const float4 xv = *(const float4*)&xs2[tm][4 * lg];                   \
      f32x4 ai = {fmaf(xv.x, wx_0, bi_0), fmaf(xv.y, wx_0, bi_0),           \
                  fmaf(xv.z, wx_0, bi_0), fmaf(xv.w, wx_0, bi_0)};          \
      f32x4 af = {fmaf(xv.x, wx_1, bi_1), fmaf(xv.y, wx_1, bi_1),           \
                  fmaf(xv.z, wx_1, bi_1), fmaf(xv.w, wx_1, bi_1)};          \
      f32x4 ag = {fmaf(xv.x, wx_2, bi_2), fmaf(xv.y, wx_2, bi_2),           \
                  fmaf(xv.z, wx_2, bi_2), fmaf(xv.w, wx_2, bi_2)};          \
      f32x4 ao = {fmaf(xv.x, wx_3, bi_3), fmaf(xv.y, wx_3, bi_3),           \
                  fmaf(xv.z, wx_3, bi_3), fmaf(xv.w, wx_3, bi_3)};          \
      MM0(0, ai) MM0(1, af) MM0(2, ag) MM0(3, ao)                           \
      FINR(0, H0, WP) FINR(1, H0, WP) FINR(2, H0, WP) FINR(3, H0, WP) }

    STAGE(0) __syncthreads();
    L0STEP(1, 0, 0) __syncthreads();  // tt=0: read zeros(parity1), write p0
    for (int it = 0; it < 255; ++it) {
      const int todd = 2 * it + 1;
      L0STEP(0, 1, (todd & 63)) __syncthreads();
      const int tev = todd + 1;
      if ((tev & 63) == 0) { STAGE(tev >> 6) __syncthreads(); }
      L0STEP(1, 0, (tev & 63)) __syncthreads();
    }
    L0STEP(0, 1, 63) __syncthreads();  // tt=511
    __syncthreads();                   // matches L1 epilogue barrier
  } else {
    // ================= LAYER-1 WAVES =================
#define DECL1(G) half8 I0h_##G, I0l_##G, I1h_##G, I1l_##G,    \
        R0h_##G, R0l_##G, R1h_##G, R1l_##G;                   \
    float bi_##G = 0.f;
    GATES(DECL1)
#define LOAD1(G)                                              \
    { loadW(Wih1, u, G, 0, lg, I0h_##G, I0l_##G);             \
      loadW(Wih1, u, G, 32, lg, I1h_##G, I1l_##G);            \
      loadW(Whh1, u, G, 0, lg, R0h_##G, R0l_##G);             \
      loadW(Whh1, u, G, 32, lg, R1h_##G, R1l_##G);            \
      if (uv) bi_##G = bih1[G * 50 + u] + bhh1[G * 50 + u]; }
    GATES(LOAD1)
    float cc0 = 0.f, cc1 = 0.f, cc2 = 0.f, cc3 = 0.f;

#define MM1(G, ACC)                                           \
    ACC = mfma16(f0, I0h_##G, ACC);                           \
    ACC = mfma16(f0, I0l_##G, ACC);                           \
    ACC = mfma16(f1, I1h_##G, ACC);                           \
    ACC = mfma16(f1, I1l_##G, ACC);                           \
    ACC = mfma16(g0, R0h_##G, ACC);                           \
    ACC = mfma16(g0, R0l_##G, ACC);                           \
    ACC = mfma16(g1, R1h_##G, ACC);                           \
    ACC = mfma16(g1, R1l_##G, ACC);

#define L1STEP(P0, R1, W1)                                                  \
    { const half8 f0 = rdfrag(&H0[P0][lane8]);                              \
      const half8 f1 = rdfrag(&H0[P0][512 + lane8]);                        \
      const half8 g0 = rdfrag(&H1[R1][lane8]);                              \
      const half8 g1 = rdfrag(&H1[R1][512 + lane8]);                        \
      f32x4 ai = {bi_0, bi_0, bi_0, bi_0};                                  \
      f32x4 af = {bi_1, bi_1, bi_1, bi_1};                                  \
      f32x4 ag = {bi_2, bi_2, bi_2, bi_2};                                  \
      f32x4 ao = {bi_3, bi_3, bi_3, bi_3};                                  \
      MM1(0, ai) MM1(1, af) MM1(2, ag) MM1(3, ao)                           \
      FINR(0, H1, W1) FINR(1, H1, W1) FINR(2, H1, W1) FINR(3, H1, W1) }

    __syncthreads(); __syncthreads();  // mirror peel barriers (tt=0 skip)
    for (int it = 0; it < 255; ++it) {
      // tt odd: h0[tt-1]=p0, h1[tt-2]=p1, write h1[tt-1]=p0
      L1STEP(0, 1, 0) __syncthreads();
      if (((2 * it + 2) & 63) == 0) __syncthreads();  // mirror stage barrier
      // tt even: h0[tt-1]=p1, h1[tt-2]=p0, write h1[tt-1]=p1
      L1STEP(1, 0, 1) __syncthreads();
    }
    L1STEP(0, 1, 0) __syncthreads();  // tt=511 -> h1[510]
    L1STEP(1, 0, 1) __syncthreads();  // epilogue -> h1[511] (parity 1)
  }

  // ---- FC head: out[b] = fc_b + sum_j fcW[j] * h1[511][b][j] ----
  if (tid < 16) {
    float s = fcb[0];
    for (int j = 0; j < 50; ++j) {
      const int idx = ((j >> 5) << 9) + (((j >> 2) & 3) << 7) + (tid << 3) +
                      (((j >> 4) & 1) << 2) + (j & 3);
      s += fcW[j] * (float)H1[1][idx];
    }
    out[bbase + tid] = s;
  }
}

extern "C" void kernel_launch(void* const* d_in, const int* in_sizes, int n_in,
                              void* d_out, int out_size, void* d_ws, size_t ws_size,
                              hipStream_t stream) {
  const float* x    = (const float*)d_in[0];
  const float* Wih0 = (const float*)d_in[1];
  const float* Whh0 = (const float*)d_in[2];
  const float* bih0 = (const float*)d_in[3];
  const float* bhh0 = (const float*)d_in[4];
  const float* Wih1 = (const float*)d_in[5];
  const float* Whh1 = (const float*)d_in[6];
  const float* bih1 = (const float*)d_in[7];
  const float* bhh1 = (const float*)d_in[8];
  const float* fcW  = (const float*)d_in[9];
  const float* fcb  = (const float*)d_in[10];
  float* out = (float*)d_out;

  const int B = out_size;          // 4096
  const int blocks = B / 16;       // 256
  lstm2_kernel<<<dim3(blocks), dim3(512), 0, stream>>>(
      x, Wih0, Whh0, bih0, bhh0, Wih1, Whh1, bih1, bhh1, fcW, fcb, out);
}

// Round 15
// 393.586 us; speedup vs baseline: 1.2325x; 1.2125x over previous
//
#include <hip/hip_runtime.h>

// 2-layer LSTM (B=4096, T=512, H=50) + FC head.
// R15 vs R14 (534 us steady; ~1650 cyc/step/SIMD of bubbles at 2 waves/SIMD;
// regs 220/wave = weights 128 AGPR + 92 VGPR pin occupancy):
//  SINGLE change: weights stored as single f16 (lo-correction planes
//  DROPPED). L1 32->16 mfma/step, L0 16->8; weight AGPRs 128->64; MFMA
//  dep-chains halve (8->4). Precision experiment: W-quant is systematic
//  (~1.4e-4 preact RMS) x recurrence amplification -> predicted absmax
//  0.8-1.3e-3 vs 1.63e-3 threshold. Fallback if FAIL: restore lo for the
//  recurrent matrices (Whh0/Whh1), keep single f16 for Wih1.
// h stays f16 (quant floor 4.88e-4), c stays f32, accum f32.
// Skeleton / barriers / parities / b128 layout byte-identical to R14.

typedef __attribute__((ext_vector_type(8))) _Float16 half8;
typedef __attribute__((ext_vector_type(4))) float f32x4;

#define LOG2E 1.44269504088896340736f

__device__ __forceinline__ float rcp_(float x) { return __builtin_amdgcn_rcpf(x); }
__device__ __forceinline__ float exp2_(float x) { return __builtin_amdgcn_exp2f(x); }
__device__ __forceinline__ float sigm(float x) {
  return rcp_(1.f + exp2_(-LOG2E * x));
}
__device__ __forceinline__ float tanh_(float x) {
  return 1.f - 2.f * rcp_(1.f + exp2_(2.f * LOG2E * x));
}
__device__ __forceinline__ f32x4 mfma16(half8 a, half8 b, f32x4 c) {
  return __builtin_amdgcn_mfma_f32_16x16x32_f16(a, b, c, 0, 0, 0);
}

union ABu16 { uint4 u; half8 v; };
__device__ __forceinline__ half8 rdfrag(const _Float16* p) {
  ABu16 t;
  t.u = *(const uint4*)p;
  return t.v;
}

// Single-f16 B-fragment of W (50x50 logical) for output column (n,gate);
// k = kbase + 16*(e>>2) + 4*lg + (e&3).
__device__ __forceinline__ half8 loadW1(const float* __restrict__ W, int n,
                                        int gate, int kbase, int lg) {
  half8 r;
#pragma unroll
  for (int e = 0; e < 8; ++e) {
    const int k = kbase + 16 * (e >> 2) + 4 * lg + (e & 3);
    const bool v = (n < 50) && (k < 50);
    r[e] = (_Float16)(v ? W[(gate * 50 + n) * 50 + k] : 0.f);
  }
  return r;
}

#define GATES(X) X(0) X(1) X(2) X(3)

// Gate finish (R12/R14 form): 4 indep sigm + 2 tanh, shallow c-chain.
#define FINR(r, PH, WPc)                                      \
  {                                                           \
    const float i_ = sigm(ai[r]), ff = sigm(af[r]);           \
    const float g_ = tanh_(ag[r]), o_ = sigm(ao[r]);          \
    cc##r = ff * cc##r + i_ * g_;                             \
    PH[WPc][woff + 8 * (r)] = (_Float16)(o_ * tanh_(cc##r));  \
  }

__global__ __launch_bounds__(512) void lstm2_kernel(
    const float* __restrict__ x,
    const float* __restrict__ Wih0, const float* __restrict__ Whh0,
    const float* __restrict__ bih0, const float* __restrict__ bhh0,
    const float* __restrict__ Wih1, const float* __restrict__ Whh1,
    const float* __restrict__ bih1, const float* __restrict__ bhh1,
    const float* __restrict__ fcW, const float* __restrict__ fcb,
    float* __restrict__ out) {
  const int tid = threadIdx.x;
  const int lane = tid & 63;
  const int wv = tid >> 6;      // wave 0..7
  const int wg = wv & 3;        // unit-group within layer role
  const bool isL1 = wv >= 4;    // waves 4-7: layer 1 (lagged one step)
  const int lg = lane >> 4;     // 0..3 (k-slice / batch-group)
  const int l15 = lane & 15;
  const int bbase = blockIdx.x * 16;

  // h planes (f16): idx(u,b) = (u>>5)*512 + ((u>>2)&3)*128 + b*8 +
  // ((u>>4)&1)*4 + (u&3). A-frag for k-tile kt = b128 at [kt*512 + 8*lane].
  __shared__ __align__(16) _Float16 H0[2][1024], H1[2][1024];
  __shared__ float xs2[64][16];    // x chunk: [t within chunk][batch]
  __shared__ float ldspad[18688];  // 74.75 KB pin -> ~87 KB total, 1 blk/CU

  ((volatile float*)ldspad)[tid] = 0.f;

  for (int i = tid; i < 1024; i += 512) {  // zero both parities of both planes
    ((unsigned int*)H0)[i] = 0u;
    ((unsigned int*)H1)[i] = 0u;
  }

  const int lane8 = lane * 8;   // f16 index of this lane's b128 A-frag slot
  const int u = 16 * wg + l15;  // this lane's output unit
  const bool uv = (u < 50);
  // write base for (u, batches 4lg..4lg+3): +8 per batch row
  const int woff = ((u >> 5) << 9) + (((u >> 2) & 3) << 7) + ((4 * lg) << 3) +
                   (((u >> 4) & 1) << 2) + (u & 3);

#define STAGE(c)                                                        \
  {                                                                     \
    const int b_ = tid >> 4, fg_ = tid & 15;                            \
    const float4 v_ = *(const float4*)&x[(size_t)(bbase + b_) * 512 +   \
                                         (c) * 64 + 4 * fg_];           \
    xs2[4 * fg_ + 0][b_] = v_.x; xs2[4 * fg_ + 1][b_] = v_.y;           \
    xs2[4 * fg_ + 2][b_] = v_.z; xs2[4 * fg_ + 3][b_] = v_.w;           \
  }

  if (!isL1) {
    // ================= LAYER-0 WAVES (tid < 256) =================
#define DECL0(G) half8 W0_##G, W1_##G; float bi_##G = 0.f, wx_##G = 0.f;
    GATES(DECL0)
#define LOAD0(G)                                              \
    { W0_##G = loadW1(Whh0, u, G, 0, lg);                     \
      W1_##G = loadW1(Whh0, u, G, 32, lg);                    \
      if (uv) {                                               \
        bi_##G = bih0[G * 50 + u] + bhh0[G * 50 + u];         \
        wx_##G = Wih0[G * 50 + u];                            \
      } }
    GATES(LOAD0)
    float cc0 = 0.f, cc1 = 0.f, cc2 = 0.f, cc3 = 0.f;

#define MM0(G, ACC)                                           \
    ACC = mfma16(f0, W0_##G, ACC);                            \
    ACC = mfma16(f1, W1_##G, ACC);

#define L0STEP(RP, WP, tm)                                                  \
    { const half8 f0 = rdfrag(&H0[RP][lane8]);                              \
      const half8 f1 = rdfrag(&H0[RP][512 + lane8]);                        \
      const float4 xv = *(const float4*)&xs2[tm][4 * lg];                   \
      f32x4 ai = {fmaf(xv.x, wx_0, bi_0), fmaf(xv.y, wx_0, bi_0),           \
                  fmaf(xv.z, wx_0, bi_0), fmaf(xv.w, wx_0, bi_0)};          \
      f32x4 af = {fmaf(xv.x, wx_1, bi_1), fmaf(xv.y, wx_1, bi_1),           \
                  fmaf(xv.z, wx_1, bi_1), fmaf(xv.w, wx_1, bi_1)};          \
      f32x4 ag = {fmaf(xv.x, wx_2, bi_2), fmaf(xv.y, wx_2, bi_2),           \
                  fmaf(xv.z, wx_2, bi_2), fmaf(xv.w, wx_2, bi_2)};          \
      f32x4 ao = {fmaf(xv.x, wx_3, bi_3), fmaf(xv.y, wx_3, bi_3),           \
                  fmaf(xv.z, wx_3, bi_3), fmaf(xv.w, wx_3, bi_3)};          \
      MM0(0, ai) MM0(1, af) MM0(2, ag) MM0(3, ao)                           \
      FINR(0, H0, WP) FINR(1, H0, WP) FINR(2, H0, WP) FINR(3, H0, WP) }

    STAGE(0) __syncthreads();
    L0STEP(1, 0, 0) __syncthreads();  // tt=0: read zeros(parity1), write p0
    for (int it = 0; it < 255; ++it) {
      const int todd = 2 * it + 1;
      L0STEP(0, 1, (todd & 63)) __syncthreads();
      const int tev = todd + 1;
      if ((tev & 63) == 0) { STAGE(tev >> 6) __syncthreads(); }
      L0STEP(1, 0, (tev & 63)) __syncthreads();
    }
    L0STEP(0, 1, 63) __syncthreads();  // tt=511
    __syncthreads();                   // matches L1 epilogue barrier
  } else {
    // ================= LAYER-1 WAVES =================
#define DECL1(G) half8 I0_##G, I1_##G, R0_##G, R1_##G; float bi_##G = 0.f;
    GATES(DECL1)
#define LOAD1(G)                                              \
    { I0_##G = loadW1(Wih1, u, G, 0, lg);                     \
      I1_##G = loadW1(Wih1, u, G, 32, lg);                    \
      R0_##G = loadW1(Whh1, u, G, 0, lg);                     \
      R1_##G = loadW1(Whh1, u, G, 32, lg);                    \
      if (uv) bi_##G = bih1[G * 50 + u] + bhh1[G * 50 + u]; }
    GATES(LOAD1)
    float cc0 = 0.f, cc1 = 0.f, cc2 = 0.f, cc3 = 0.f;

#define MM1(G, ACC)                                           \
    ACC = mfma16(f0, I0_##G, ACC);                            \
    ACC = mfma16(f1, I1_##G, ACC);                            \
    ACC = mfma16(g0, R0_##G, ACC);                            \
    ACC = mfma16(g1, R1_##G, ACC);

#define L1STEP(P0, R1p, W1p)                                                \
    { const half8 f0 = rdfrag(&H0[P0][lane8]);                              \
      const half8 f1 = rdfrag(&H0[P0][512 + lane8]);                        \
      const half8 g0 = rdfrag(&H1[R1p][lane8]);                             \
      const half8 g1 = rdfrag(&H1[R1p][512 + lane8]);                       \
      f32x4 ai = {bi_0, bi_0, bi_0, bi_0};                                  \
      f32x4 af = {bi_1, bi_1, bi_1, bi_1};                                  \
      f32x4 ag = {bi_2, bi_2, bi_2, bi_2};                                  \
      f32x4 ao = {bi_3, bi_3, bi_3, bi_3};                                  \
      MM1(0, ai) MM1(1, af) MM1(2, ag) MM1(3, ao)                           \
      FINR(0, H1, W1p) FINR(1, H1, W1p) FINR(2, H1, W1p) FINR(3, H1, W1p) }

    __syncthreads(); __syncthreads();  // mirror peel barriers (tt=0 skip)
    for (int it = 0; it < 255; ++it) {
      // tt odd: h0[tt-1]=p0, h1[tt-2]=p1, write h1[tt-1]=p0
      L1STEP(0, 1, 0) __syncthreads();
      if (((2 * it + 2) & 63) == 0) __syncthreads();  // mirror stage barrier
      // tt even: h0[tt-1]=p1, h1[tt-2]=p0, write h1[tt-1]=p1
      L1STEP(1, 0, 1) __syncthreads();
    }
    L1STEP(0, 1, 0) __syncthreads();  // tt=511 -> h1[510]
    L1STEP(1, 0, 1) __syncthreads();  // epilogue -> h1[511] (parity 1)
  }

  // ---- FC head: out[b] = fc_b + sum_j fcW[j] * h1[511][b][j] ----
  if (tid < 16) {
    float s = fcb[0];
    for (int j = 0; j < 50; ++j) {
      const int idx = ((j >> 5) << 9) + (((j >> 2) & 3) << 7) + (tid << 3) +
                      (((j >> 4) & 1) << 2) + (j & 3);
      s += fcW[j] * (float)H1[1][idx];
    }
    out[bbase + tid] = s;
  }
}

extern "C" void kernel_launch(void* const* d_in, const int* in_sizes, int n_in,
                              void* d_out, int out_size, void* d_ws, size_t ws_size,
                              hipStream_t stream) {
  const float* x    = (const float*)d_in[0];
  const float* Wih0 = (const float*)d_in[1];
  const float* Whh0 = (const float*)d_in[2];
  const float* bih0 = (const float*)d_in[3];
  const float* bhh0 = (const float*)d_in[4];
  const float* Wih1 = (const float*)d_in[5];
  const float* Whh1 = (const float*)d_in[6];
  const float* bih1 = (const float*)d_in[7];
  const float* bhh1 = (const float*)d_in[8];
  const float* fcW  = (const float*)d_in[9];
  const float* fcb  = (const float*)d_in[10];
  float* out = (float*)d_out;

  const int B = out_size;          // 4096
  const int blocks = B / 16;       // 256
  lstm2_kernel<<<dim3(blocks), dim3(512), 0, stream>>>(
      x, Wih0, Whh0, bih0, bhh0, Wih1, Whh1, bih1, bhh1, fcW, fcb, out);
}

// Round 16
// 391.248 us; speedup vs baseline: 1.2399x; 1.0060x over previous
//
#include <hip/hip_runtime.h>

// 2-layer LSTM (B=4096, T=512, H=50) + FC head.
// R16 vs R15 (437 us steady; ~70% bubbles at 2 waves/SIMD; L1 2x L0 work):
//  3-STAGE PIPELINE, 12 waves (768 thr) = 3 waves/SIMD:
//   role 0 (wv 0-3):  L0  computes h0[s]          (8 MFMA + FIN)
//   role 1 (wv 4-7):  I   computes P[s-1]=Wih1*h0 (8 MFMA, f32 partials->LDS)
//   role 2 (wv 8-11): R   computes h1[s-2]=FIN(P[s-2]+Whh1*h1[s-3])
//  One barrier/step; 2 epilogue steps (s=512,513). Partial exchange is
//  lane-sequential b128 (conflict-free). L0 x-term moved post-MFMA.
//  Reg audit: ~80 VGPR + 32 AGPR weights = ~112 unified <= 170 (=512/3);
//  12 waves + LDS pin (1 blk/CU) make 3/SIMD the only consistent target —
//  R10's allocator failure (4/SIMD cap 128 < demand) arithmetically excluded.
// Math identical to R15 -> absmax 4.882812e-4 expected unchanged.

typedef __attribute__((ext_vector_type(8))) _Float16 half8;
typedef __attribute__((ext_vector_type(4))) float f32x4;

#define LOG2E 1.44269504088896340736f

__device__ __forceinline__ float rcp_(float x) { return __builtin_amdgcn_rcpf(x); }
__device__ __forceinline__ float exp2_(float x) { return __builtin_amdgcn_exp2f(x); }
__device__ __forceinline__ float sigm(float x) {
  return rcp_(1.f + exp2_(-LOG2E * x));
}
__device__ __forceinline__ float tanh_(float x) {
  return 1.f - 2.f * rcp_(1.f + exp2_(2.f * LOG2E * x));
}
__device__ __forceinline__ f32x4 mfma16(half8 a, half8 b, f32x4 c) {
  return __builtin_amdgcn_mfma_f32_16x16x32_f16(a, b, c, 0, 0, 0);
}

union ABu16 { uint4 u; half8 v; };
__device__ __forceinline__ half8 rdfrag(const _Float16* p) {
  ABu16 t;
  t.u = *(const uint4*)p;
  return t.v;
}

// Single-f16 B-fragment of W (50x50 logical) for output column (n,gate);
// k = kbase + 16*(e>>2) + 4*lg + (e&3).
__device__ __forceinline__ half8 loadW1(const float* __restrict__ W, int n,
                                        int gate, int kbase, int lg) {
  half8 r;
#pragma unroll
  for (int e = 0; e < 8; ++e) {
    const int k = kbase + 16 * (e >> 2) + 4 * lg + (e & 3);
    const bool v = (n < 50) && (k < 50);
    r[e] = (_Float16)(v ? W[(gate * 50 + n) * 50 + k] : 0.f);
  }
  return r;
}

__global__ __launch_bounds__(768) void lstm2_kernel(
    const float* __restrict__ x,
    const float* __restrict__ Wih0, const float* __restrict__ Whh0,
    const float* __restrict__ bih0, const float* __restrict__ bhh0,
    const float* __restrict__ Wih1, const float* __restrict__ Whh1,
    const float* __restrict__ bih1, const float* __restrict__ bhh1,
    const float* __restrict__ fcW, const float* __restrict__ fcb,
    float* __restrict__ out) {
  const int tid = threadIdx.x;
  const int lane = tid & 63;
  const int wv = tid >> 6;       // wave 0..11
  const int role = wv >> 2;      // 0 = L0, 1 = I, 2 = R
  const int wg = wv & 3;         // unit-group within role
  const int lg = lane >> 4;      // 0..3 (k-slice / batch-group)
  const int l15 = lane & 15;
  const int bbase = blockIdx.x * 16;

  // h planes (f16): idx(u,b) = (u>>5)*512 + ((u>>2)&3)*128 + b*8 +
  // ((u>>4)&1)*4 + (u&3). A-frag for k-tile kt = b128 at [kt*512 + 8*lane].
  __shared__ __align__(16) _Float16 H0[2][1024], H1[2][1024];
  // f32 partials: [parity][gate*1024 + wg*256 + lane*4] (lane-sequential b128)
  __shared__ __align__(16) float Pbuf[2][4096];
  __shared__ float xs2[64][16];    // x chunk: [t within chunk][batch]
  __shared__ float ldspad[10240];  // 40 KB pin -> 84 KB total -> 1 blk/CU

  ((volatile float*)ldspad)[tid] = 0.f;

  for (int i = tid; i < 1024; i += 768) {  // zero both parities of both planes
    ((unsigned int*)H0)[i] = 0u;
    ((unsigned int*)H1)[i] = 0u;
  }

  const int lane8 = lane * 8;   // f16 index of this lane's b128 A-frag slot
  const int u = 16 * wg + l15;  // this lane's output unit
  const bool uv = (u < 50);
  // h write base for (u, batches 4lg..4lg+3): +8 per batch row
  const int woff = ((u >> 5) << 9) + (((u >> 2) & 3) << 7) + ((4 * lg) << 3) +
                   (((u >> 4) & 1) << 2) + (u & 3);
  const int pidx = wg * 256 + lane * 4;  // f32 index within a gate plane

#define STAGE(c)                                                        \
  {                                                                     \
    const int b_ = tid >> 4, fg_ = tid & 15;                            \
    const float4 v_ = *(const float4*)&x[(size_t)(bbase + b_) * 512 +   \
                                         (c) * 64 + 4 * fg_];           \
    xs2[4 * fg_ + 0][b_] = v_.x; xs2[4 * fg_ + 1][b_] = v_.y;           \
    xs2[4 * fg_ + 2][b_] = v_.z; xs2[4 * fg_ + 3][b_] = v_.w;           \
  }

  if (role == 0) {
    // ============ L0 waves: h0[s] = FIN(Whh0*h0[s-1] + x*wx + b) ============
    half8 W0_0, W1_0, W0_1, W1_1, W0_2, W1_2, W0_3, W1_3;
    float bi_0 = 0.f, bi_1 = 0.f, bi_2 = 0.f, bi_3 = 0.f;
    float wx_0 = 0.f, wx_1 = 0.f, wx_2 = 0.f, wx_3 = 0.f;
    W0_0 = loadW1(Whh0, u, 0, 0, lg);  W1_0 = loadW1(Whh0, u, 0, 32, lg);
    W0_1 = loadW1(Whh0, u, 1, 0, lg);  W1_1 = loadW1(Whh0, u, 1, 32, lg);
    W0_2 = loadW1(Whh0, u, 2, 0, lg);  W1_2 = loadW1(Whh0, u, 2, 32, lg);
    W0_3 = loadW1(Whh0, u, 3, 0, lg);  W1_3 = loadW1(Whh0, u, 3, 32, lg);
    if (uv) {
      bi_0 = bih0[0 * 50 + u] + bhh0[0 * 50 + u]; wx_0 = Wih0[0 * 50 + u];
      bi_1 = bih0[1 * 50 + u] + bhh0[1 * 50 + u]; wx_1 = Wih0[1 * 50 + u];
      bi_2 = bih0[2 * 50 + u] + bhh0[2 * 50 + u]; wx_2 = Wih0[2 * 50 + u];
      bi_3 = bih0[3 * 50 + u] + bhh0[3 * 50 + u]; wx_3 = Wih0[3 * 50 + u];
    }
    float cc0 = 0.f, cc1 = 0.f, cc2 = 0.f, cc3 = 0.f;

#define FIN0(r, xr, WPc)                                              \
    { const float i_ = sigm(ai[r] + (xr) * wx_0);                     \
      const float ff = sigm(af[r] + (xr) * wx_1);                     \
      const float g_ = tanh_(ag[r] + (xr) * wx_2);                    \
      const float o_ = sigm(ao[r] + (xr) * wx_3);                     \
      cc##r = ff * cc##r + i_ * g_;                                   \
      H0[WPc][woff + 8 * (r)] = (_Float16)(o_ * tanh_(cc##r)); }

#define L0STEP(RP, WP, tm)                                            \
    { const half8 f0 = rdfrag(&H0[RP][lane8]);                        \
      const half8 f1 = rdfrag(&H0[RP][512 + lane8]);                  \
      f32x4 ai = {bi_0, bi_0, bi_0, bi_0};                            \
      f32x4 af = {bi_1, bi_1, bi_1, bi_1};                            \
      f32x4 ag = {bi_2, bi_2, bi_2, bi_2};                            \
      f32x4 ao = {bi_3, bi_3, bi_3, bi_3};                            \
      ai = mfma16(f0, W0_0, ai); ai = mfma16(f1, W1_0, ai);           \
      af = mfma16(f0, W0_1, af); af = mfma16(f1, W1_1, af);           \
      ag = mfma16(f0, W0_2, ag); ag = mfma16(f1, W1_2, ag);           \
      ao = mfma16(f0, W0_3, ao); ao = mfma16(f1, W1_3, ao);           \
      const float4 xv = *(const float4*)&xs2[tm][4 * lg];             \
      FIN0(0, xv.x, WP) FIN0(1, xv.y, WP)                             \
      FIN0(2, xv.z, WP) FIN0(3, xv.w, WP) }

    for (int it = 0; it <= 256; ++it) {
      if ((it & 31) == 0 && it < 256) { STAGE(it >> 5) __syncthreads(); }
      if (it < 256) L0STEP(1, 0, ((2 * it) & 63))       // even s=2it
      __syncthreads();
      if (it < 256) L0STEP(0, 1, ((2 * it + 1) & 63))   // odd s=2it+1
      __syncthreads();
    }
  } else if (role == 1) {
    // ============ I waves: P[s-1] = Wih1 * h0[s-1] (f32 partials) ============
    half8 I0_0, I1_0, I0_1, I1_1, I0_2, I1_2, I0_3, I1_3;
    I0_0 = loadW1(Wih1, u, 0, 0, lg);  I1_0 = loadW1(Wih1, u, 0, 32, lg);
    I0_1 = loadW1(Wih1, u, 1, 0, lg);  I1_1 = loadW1(Wih1, u, 1, 32, lg);
    I0_2 = loadW1(Wih1, u, 2, 0, lg);  I1_2 = loadW1(Wih1, u, 2, 32, lg);
    I0_3 = loadW1(Wih1, u, 3, 0, lg);  I1_3 = loadW1(Wih1, u, 3, 32, lg);

#define ISTEP(RP, WPp)                                                \
    { const half8 f0 = rdfrag(&H0[RP][lane8]);                        \
      const half8 f1 = rdfrag(&H0[RP][512 + lane8]);                  \
      f32x4 a0 = {0.f, 0.f, 0.f, 0.f};                                \
      f32x4 a1 = a0, a2 = a0, a3 = a0;                                \
      a0 = mfma16(f0, I0_0, a0); a0 = mfma16(f1, I1_0, a0);           \
      a1 = mfma16(f0, I0_1, a1); a1 = mfma16(f1, I1_1, a1);           \
      a2 = mfma16(f0, I0_2, a2); a2 = mfma16(f1, I1_2, a2);           \
      a3 = mfma16(f0, I0_3, a3); a3 = mfma16(f1, I1_3, a3);           \
      *(f32x4*)&Pbuf[WPp][pidx]        = a0;                          \
      *(f32x4*)&Pbuf[WPp][1024 + pidx] = a1;                          \
      *(f32x4*)&Pbuf[WPp][2048 + pidx] = a2;                          \
      *(f32x4*)&Pbuf[WPp][3072 + pidx] = a3; }

    for (int it = 0; it <= 256; ++it) {
      if ((it & 31) == 0 && it < 256) { __syncthreads(); }
      if (it >= 1) ISTEP(1, 1)      // even s: P[s-1] (odd idx), rd h0 par1
      __syncthreads();
      if (it < 256) ISTEP(0, 0)     // odd s: P[s-1] (even idx), rd h0 par0
      __syncthreads();
    }
  } else {
    // ============ R waves: h1[s-2] = FIN(P[s-2] + Whh1*h1[s-3]) ============
    half8 R0_0, R1_0, R0_1, R1_1, R0_2, R1_2, R0_3, R1_3;
    float bi_0 = 0.f, bi_1 = 0.f, bi_2 = 0.f, bi_3 = 0.f;
    R0_0 = loadW1(Whh1, u, 0, 0, lg);  R1_0 = loadW1(Whh1, u, 0, 32, lg);
    R0_1 = loadW1(Whh1, u, 1, 0, lg);  R1_1 = loadW1(Whh1, u, 1, 32, lg);
    R0_2 = loadW1(Whh1, u, 2, 0, lg);  R1_2 = loadW1(Whh1, u, 2, 32, lg);
    R0_3 = loadW1(Whh1, u, 3, 0, lg);  R1_3 = loadW1(Whh1, u, 3, 32, lg);
    if (uv) {
      bi_0 = bih1[0 * 50 + u] + bhh1[0 * 50 + u];
      bi_1 = bih1[1 * 50 + u] + bhh1[1 * 50 + u];
      bi_2 = bih1[2 * 50 + u] + bhh1[2 * 50 + u];
      bi_3 = bih1[3 * 50 + u] + bhh1[3 * 50 + u];
    }
    float cc0 = 0.f, cc1 = 0.f, cc2 = 0.f, cc3 = 0.f;

#define FINR2(r, WH)                                                  \
    { const float i_ = sigm(ai[r] + p0[r]);                           \
      const float ff = sigm(af[r] + p1[r]);                           \
      const float g_ = tanh_(ag[r] + p2[r]);                          \
      const float o_ = sigm(ao[r] + p3[r]);                           \
      cc##r = ff * cc##r + i_ * g_;                                   \
      H1[WH][woff + 8 * (r)] = (_Float16)(o_ * tanh_(cc##r)); }

#define RSTEP(PP, RH, WH)                                             \
    { const half8 g0 = rdfrag(&H1[RH][lane8]);                        \
      const half8 g1 = rdfrag(&H1[RH][512 + lane8]);                  \
      const f32x4 p0 = *(const f32x4*)&Pbuf[PP][pidx];                \
      const f32x4 p1 = *(const f32x4*)&Pbuf[PP][1024 + pidx];         \
      const f32x4 p2 = *(const f32x4*)&Pbuf[PP][2048 + pidx];         \
      const f32x4 p3 = *(const f32x4*)&Pbuf[PP][3072 + pidx];         \
      f32x4 ai = {bi_0, bi_0, bi_0, bi_0};                            \
      f32x4 af = {bi_1, bi_1, bi_1, bi_1};                            \
      f32x4 ag = {bi_2, bi_2, bi_2, bi_2};                            \
      f32x4 ao = {bi_3, bi_3, bi_3, bi_3};                            \
      ai = mfma16(g0, R0_0, ai); ai = mfma16(g1, R1_0, ai);           \
      af = mfma16(g0, R0_1, af); af = mfma16(g1, R1_1, af);           \
      ag = mfma16(g0, R0_2, ag); ag = mfma16(g1, R1_2, ag);           \
      ao = mfma16(g0, R0_3, ao); ao = mfma16(g1, R1_3, ao);           \
      FINR2(0, WH) FINR2(1, WH) FINR2(2, WH) FINR2(3, WH) }

    for (int it = 0; it <= 256; ++it) {
      if ((it & 31) == 0 && it < 256) { __syncthreads(); }
      if (it >= 1) RSTEP(0, 1, 0)   // even s: h1[s-2] (even idx)
      __syncthreads();
      if (it >= 1) RSTEP(1, 0, 1)   // odd s: h1[s-2] (odd idx)
      __syncthreads();
    }
  }

  // ---- FC head: out[b] = fc_b + sum_j fcW[j] * h1[511][b][j] (parity 1) ----
  if (tid < 16) {
    float s = fcb[0];
    for (int j = 0; j < 50; ++j) {
      const int idx = ((j >> 5) << 9) + (((j >> 2) & 3) << 7) + (tid << 3) +
                      (((j >> 4) & 1) << 2) + (j & 3);
      s += fcW[j] * (float)H1[1][idx];
    }
    out[bbase + tid] = s;
  }
}

extern "C" void kernel_launch(void* const* d_in, const int* in_sizes, int n_in,
                              void* d_out, int out_size, void* d_ws, size_t ws_size,
                              hipStream_t stream) {
  const float* x    = (const float*)d_in[0];
  const float* Wih0 = (const float*)d_in[1];
  const float* Whh0 = (const float*)d_in[2];
  const float* bih0 = (const float*)d_in[3];
  const float* bhh0 = (const float*)d_in[4];
  const float* Wih1 = (const float*)d_in[5];
  const float* Whh1 = (const float*)d_in[6];
  const float* bih1 = (const float*)d_in[7];
  const float* bhh1 = (const float*)d_in[8];
  const float* fcW  = (const float*)d_in[9];
  const float* fcb  = (const float*)d_in[10];
  float* out = (float*)d_out;

  const int B = out_size;          // 4096
  const int blocks = B / 16;       // 256
  lstm2_kernel<<<dim3(blocks), dim3(768), 0, stream>>>(
      x, Wih0, Whh0, bih0, bhh0, Wih1, Whh1, bih1, bhh1, fcW, fcb, out);
}